// Round 14
// baseline (246.564 us; speedup 1.0000x reference)
//
#include <hip/hip_runtime.h>
#include <stdint.h>

#define DI __device__ __forceinline__

typedef unsigned short u16;
typedef unsigned int   u32;
typedef __attribute__((ext_vector_type(8))) short short8;
typedef __attribute__((ext_vector_type(4))) float f32x4;

// ---- constants (problem shape hardcoded) ----
// B=2, S=2048, HID=2048, HQ=16, HKV=8, D=128

DI u16 f2bf(float f) {
    u32 u = __float_as_uint(f);
    u32 r = u + 0x7fff + ((u >> 16) & 1);   // RNE
    return (u16)(r >> 16);
}
DI u32 pk2bf(float a, float b) {
    return (u32)f2bf(a) | ((u32)f2bf(b) << 16);
}
DI float bf2f(u16 h) { return __uint_as_float(((u32)h) << 16); }

DI f32x4 mfma16(short8 a, short8 b, f32x4 c) {
    return __builtin_amdgcn_mfma_f32_16x16x32_bf16(a, b, c, 0, 0, 0);
}

DI void gload_lds16(const void* g, void* l) {
    __builtin_amdgcn_global_load_lds(
        (const __attribute__((address_space(1))) void*)g,
        (__attribute__((address_space(3))) void*)l, 16, 0, 0);
}

// rotate 4 bf16 (re,im) pairs by cos/sin (float4), scale folded into c/s
DI short8 rope8(short8 raw, const float* cp, const float* sp, float osc) {
    float4 c4 = *(const float4*)cp;
    float4 s4 = *(const float4*)sp;
    u32* rp = (u32*)&raw;
#pragma unroll
    for (int p = 0; p < 4; p++) {
        u32 v = rp[p];
        float re = __uint_as_float(v << 16);
        float im = __uint_as_float(v & 0xffff0000u);
        float cc = ((const float*)&c4)[p] * osc;
        float ss = ((const float*)&s4)[p] * osc;
        rp[p] = pk2bf(re * cc - im * ss, re * ss + im * cc);
    }
    return raw;
}

// ---------------- convert x f32 -> bf16 ----------------
__global__ __launch_bounds__(256) void cvt_x(const float* __restrict__ x,
                                             u16* __restrict__ o, int n4) {
    int i = blockIdx.x * 256 + threadIdx.x;
    if (i >= n4) return;
    float4 v = *(const float4*)(x + (size_t)i * 4);
    uint2 p; p.x = pk2bf(v.x, v.y); p.y = pk2bf(v.z, v.w);
    *(uint2*)(o + (size_t)i * 4) = p;
}

// ---------------- all 4 weights: W [K][N] f32 -> WT [N][K] bf16, one launch ----
__global__ __launch_bounds__(256) void transpose_cvt4(const float* __restrict__ W0,
                                                      const float* __restrict__ W1,
                                                      const float* __restrict__ W2,
                                                      const float* __restrict__ W3,
                                                      u16* __restrict__ D0,
                                                      u16* __restrict__ D1,
                                                      u16* __restrict__ D2,
                                                      u16* __restrict__ D3) {
    const float* W; u16* D; int N;
    switch (blockIdx.z) {
        case 0:  W = W0; D = D0; N = 2048; break;
        case 1:  W = W1; D = D1; N = 1024; break;
        case 2:  W = W2; D = D2; N = 1024; break;
        default: W = W3; D = D3; N = 2048; break;
    }
    if ((int)blockIdx.x >= (N >> 6)) return;
    const int K = 2048;
    __shared__ u16 tl[64][65];
    int tx = threadIdx.x & 15, ty = threadIdx.x >> 4;
    int tc = blockIdx.x * 64, tr = blockIdx.y * 64;
#pragma unroll
    for (int i = 0; i < 4; i++) {
        int r = tr + ty + i * 16;
        float4 v = *(const float4*)&W[(size_t)r * N + tc + tx * 4];
        tl[tx*4+0][ty+i*16] = f2bf(v.x);
        tl[tx*4+1][ty+i*16] = f2bf(v.y);
        tl[tx*4+2][ty+i*16] = f2bf(v.z);
        tl[tx*4+3][ty+i*16] = f2bf(v.w);
    }
    __syncthreads();
#pragma unroll
    for (int i = 0; i < 4; i++) {
        int n = tc + ty + i * 16;
        uint2 p;
        p.x = (u32)tl[ty+i*16][tx*4+0] | ((u32)tl[ty+i*16][tx*4+1] << 16);
        p.y = (u32)tl[ty+i*16][tx*4+2] | ((u32)tl[ty+i*16][tx*4+3] << 16);
        *(uint2*)&D[(size_t)n * K + tr + tx * 4] = p;
    }
}

// ---------------- RoPE in-place on bf16 [tok][H*128] (K only) ----------------
__global__ __launch_bounds__(256) void rope_kernel(u16* __restrict__ buf,
                                                   const float* __restrict__ fc,
                                                   const float* __restrict__ fs,
                                                   int H, int tokshift, int total,
                                                   float oscale) {
    int idx = blockIdx.x * 256 + threadIdx.x;
    if (idx >= total) return;
    int tok = idx >> tokshift;
    int rem = idx & ((1 << tokshift) - 1);
    int h = rem >> 6, j = rem & 63;
    int s = tok & 2047;
    size_t a = ((size_t)tok * H + h) * 128 + 2 * j;
    u32 v = *(u32*)(buf + a);
    float re = bf2f((u16)(v & 0xffff));
    float im = bf2f((u16)(v >> 16));
    float c = fc[s * 64 + j], sn = fs[s * 64 + j];
    *(u32*)(buf + a) = pk2bf((re * c - im * sn) * oscale,
                             (re * sn + im * c) * oscale);
}

// ---------------- QKV GEMM, 2-phase counted-vmcnt (BM=128 BN=256) ----------
// A[4096][2048]bf16 * WqkvT[4096][2048]^T; Q/K/V^T split epilogue.
// 512 blocks, 512 thr = 8 waves (2M x 4N), per-wave 64x64, K-step 64.
// Same proven pipeline as gemm_wo8: LDS 96KB = 2 buf x (A 16KB + B 32KB);
// ph1 {stage B(t+1) || read A + B01 || 16 MFMA}; ph2 {stage A(t+2) into cur
// || 16 MFMA}; boundary vmcnt(2) — never drain to 0.
__global__ __launch_bounds__(512) void gemm_qkv2(const u16* __restrict__ A,
                                                 const u16* __restrict__ BT,
                                                 u16* __restrict__ Qo,
                                                 u16* __restrict__ Ko,
                                                 u16* __restrict__ Vo) {
    __shared__ __align__(16) u16 SM[49152];   // 96 KB
    char* smb = (char*)SM;
    const int tid = threadIdx.x;
    const int w = tid >> 6, l = tid & 63;
    const int l15 = l & 15, lh = l >> 4;
    const int wr = w >> 2, wc = w & 3;        // 2M x 4N

    // XCD-bijective swizzle for nwg=512: each XCD gets a contiguous 4bx x 16by chunk
    const int bid = blockIdx.x;
    const int sw = (bid & 7) * 64 + (bid >> 3);
    const int bx = sw & 15, by = sw >> 4;     // bx: 16 N-tiles, by: 32 M-tiles

    const char* Ag = (const char*)A  + (size_t)(by * 128) * 4096;
    const char* Bg = (const char*)BT + (size_t)(bx * 256) * 4096;

    const int r0 = tid >> 3;                                   // 64 rows/issue
    const int c0 = ((tid & 7) << 4) ^ (((tid >> 5) & 1) << 5); // src pre-swizzle
    const int wb = w << 10;

#define STG_WA(tt, bb) do {                                                 \
        const char* s_ = Ag + (size_t)r0 * 4096 + (tt) * 128 + c0;          \
        char* d_ = smb + (bb) * 49152 + wb;                                 \
        gload_lds16(s_, d_);                                                \
        gload_lds16(s_ + (size_t)64 * 4096, d_ + 8192);                     \
    } while (0)
#define STG_WB(tt, bb) do {                                                 \
        const char* s_ = Bg + (size_t)r0 * 4096 + (tt) * 128 + c0;          \
        char* d_ = smb + (bb) * 49152 + 16384 + wb;                         \
        gload_lds16(s_, d_);                                                \
        gload_lds16(s_ + (size_t)64 * 4096, d_ + 8192);                     \
        gload_lds16(s_ + (size_t)128 * 4096, d_ + 16384);                   \
        gload_lds16(s_ + (size_t)192 * 4096, d_ + 24576);                   \
    } while (0)

    const int aoff = l15 * 128 + ((lh * 16) ^ (((l15 >> 2) & 1) << 5));

    const f32x4 fz = {0.f, 0.f, 0.f, 0.f};
    f32x4 acc[4][4];
#pragma unroll
    for (int m = 0; m < 4; m++)
#pragma unroll
        for (int n = 0; n < 4; n++) acc[m][n] = fz;

    STG_WA(0, 0); STG_WB(0, 0);
    STG_WA(1, 1);
    asm volatile("s_waitcnt vmcnt(2)" ::: "memory");
    __builtin_amdgcn_s_barrier();

    for (int t = 0; t < 32; ++t) {
        const int cur = t & 1;
        const int t1 = t + 1 < 32 ? t + 1 : 31;
        const int t2 = t + 2 < 32 ? t + 2 : 31;
        const char* Ab = smb + cur * 49152 + wr * 8192 + aoff;
        const char* Bb = smb + cur * 49152 + 16384 + wc * 8192 + aoff;
        short8 aF[4][2], bF[4][2];

        // ---- ph1: stage B(t+1) -> buf cur^1; read A (all) + B n0-1; MFMA 16
        STG_WB(t1, cur ^ 1);
#pragma unroll
        for (int m = 0; m < 4; m++) {
            aF[m][0] = *(const short8*)(Ab + m * 2048);
            aF[m][1] = *(const short8*)(Ab + m * 2048 + 64);
        }
#pragma unroll
        for (int n = 0; n < 2; n++) {
            bF[n][0] = *(const short8*)(Bb + n * 2048);
            bF[n][1] = *(const short8*)(Bb + n * 2048 + 64);
        }
        __builtin_amdgcn_s_setprio(1);
#pragma unroll
        for (int m = 0; m < 4; m++)
#pragma unroll
            for (int n = 0; n < 2; n++) {
                acc[m][n] = mfma16(aF[m][0], bF[n][0], acc[m][n]);
                acc[m][n] = mfma16(aF[m][1], bF[n][1], acc[m][n]);
            }
        __builtin_amdgcn_s_setprio(0);
        __builtin_amdgcn_s_barrier();

        // ---- ph2: stage A(t+2) -> buf cur (A fully consumed in ph1); MFMA 16
        STG_WA(t2, cur);
#pragma unroll
        for (int n = 2; n < 4; n++) {
            bF[n][0] = *(const short8*)(Bb + n * 2048);
            bF[n][1] = *(const short8*)(Bb + n * 2048 + 64);
        }
        __builtin_amdgcn_s_setprio(1);
#pragma unroll
        for (int m = 0; m < 4; m++)
#pragma unroll
            for (int n = 2; n < 4; n++) {
                acc[m][n] = mfma16(aF[m][0], bF[n][0], acc[m][n]);
                acc[m][n] = mfma16(aF[m][1], bF[n][1], acc[m][n]);
            }
        __builtin_amdgcn_s_setprio(0);
        asm volatile("s_waitcnt vmcnt(2)" ::: "memory");
        __builtin_amdgcn_s_barrier();
    }
#undef STG_WA
#undef STG_WB

    // epilogue: rows = tokens, cols = QKV features (2048 Q | 1024 K | 1024 V)
    const int rbase = by * 128 + wr * 64 + lh * 4;
    const int cbase = bx * 256 + wc * 64 + l15;
    if (bx < 8) {                       // Q [tok][2048]
#pragma unroll
        for (int m = 0; m < 4; m++)
#pragma unroll
            for (int j = 0; j < 4; j++) {
                size_t ro = (size_t)(rbase + m * 16 + j) * 2048 + cbase;
#pragma unroll
                for (int n = 0; n < 4; n++)
                    Qo[ro + n * 16] = f2bf(acc[m][n][j]);
            }
    } else if (bx < 12) {               // K [tok][1024]
        const int ck = cbase - 2048;
#pragma unroll
        for (int m = 0; m < 4; m++)
#pragma unroll
            for (int j = 0; j < 4; j++) {
                size_t ro = (size_t)(rbase + m * 16 + j) * 1024 + ck;
#pragma unroll
                for (int n = 0; n < 4; n++)
                    Ko[ro + n * 16] = f2bf(acc[m][n][j]);
            }
    } else {                            // V -> V^T[b][h2][d][s]
#pragma unroll
        for (int m = 0; m < 4; m++)
#pragma unroll
            for (int n = 0; n < 4; n++) {
                int tok = rbase + m * 16;
                int c = cbase + n * 16 - 3072;
                int bb2 = tok >> 11, ss = tok & 2047;
                int h2 = c >> 7, d = c & 127;
                uint2 v;
                v.x = pk2bf(acc[m][n][0], acc[m][n][1]);
                v.y = pk2bf(acc[m][n][2], acc[m][n][3]);
                *(uint2*)(Vo + (size_t)((bb2 * 8 + h2) * 128 + d) * 2048 + ss) = v;
            }
    }
}

// ---------------- Wo GEMM, 2-phase counted-vmcnt template (BM=128 BN=256) ----
__global__ __launch_bounds__(512) void gemm_wo8(const u16* __restrict__ A,
                                                const u16* __restrict__ BT,
                                                float* __restrict__ Of) {
    __shared__ __align__(16) u16 SM[49152];   // 96 KB
    char* smb = (char*)SM;
    const int tid = threadIdx.x;
    const int w = tid >> 6, l = tid & 63;
    const int l15 = l & 15, lh = l >> 4;
    const int wr = w >> 2, wc = w & 3;        // 2M x 4N

    const int bid = blockIdx.x;
    const int sw = (bid & 7) * 32 + (bid >> 3);
    const int bx = sw & 7, by = sw >> 3;      // bx: 8 N-tiles, by: 32 M-tiles

    const char* Ag = (const char*)A  + (size_t)(by * 128) * 4096;
    const char* Bg = (const char*)BT + (size_t)(bx * 256) * 4096;

    const int r0 = tid >> 3;                                   // 64 rows/issue
    const int c0 = ((tid & 7) << 4) ^ (((tid >> 5) & 1) << 5); // src pre-swizzle
    const int wb = w << 10;

#define STG_WA(tt, bb) do {                                                 \
        const char* s_ = Ag + (size_t)r0 * 4096 + (tt) * 128 + c0;          \
        char* d_ = smb + (bb) * 49152 + wb;                                 \
        gload_lds16(s_, d_);                                                \
        gload_lds16(s_ + (size_t)64 * 4096, d_ + 8192);                     \
    } while (0)
#define STG_WB(tt, bb) do {                                                 \
        const char* s_ = Bg + (size_t)r0 * 4096 + (tt) * 128 + c0;          \
        char* d_ = smb + (bb) * 49152 + 16384 + wb;                         \
        gload_lds16(s_, d_);                                                \
        gload_lds16(s_ + (size_t)64 * 4096, d_ + 8192);                     \
        gload_lds16(s_ + (size_t)128 * 4096, d_ + 16384);                   \
        gload_lds16(s_ + (size_t)192 * 4096, d_ + 24576);                   \
    } while (0)

    const int aoff = l15 * 128 + ((lh * 16) ^ (((l15 >> 2) & 1) << 5));

    const f32x4 fz = {0.f, 0.f, 0.f, 0.f};
    f32x4 acc[4][4];
#pragma unroll
    for (int m = 0; m < 4; m++)
#pragma unroll
        for (int n = 0; n < 4; n++) acc[m][n] = fz;

    STG_WA(0, 0); STG_WB(0, 0);
    STG_WA(1, 1);
    asm volatile("s_waitcnt vmcnt(2)" ::: "memory");
    __builtin_amdgcn_s_barrier();

    for (int t = 0; t < 32; ++t) {
        const int cur = t & 1;
        const int t1 = t + 1 < 32 ? t + 1 : 31;
        const int t2 = t + 2 < 32 ? t + 2 : 31;
        const char* Ab = smb + cur * 49152 + wr * 8192 + aoff;
        const char* Bb = smb + cur * 49152 + 16384 + wc * 8192 + aoff;
        short8 aF[4][2], bF[4][2];

        STG_WB(t1, cur ^ 1);
#pragma unroll
        for (int m = 0; m < 4; m++) {
            aF[m][0] = *(const short8*)(Ab + m * 2048);
            aF[m][1] = *(const short8*)(Ab + m * 2048 + 64);
        }
#pragma unroll
        for (int n = 0; n < 2; n++) {
            bF[n][0] = *(const short8*)(Bb + n * 2048);
            bF[n][1] = *(const short8*)(Bb + n * 2048 + 64);
        }
        __builtin_amdgcn_s_setprio(1);
#pragma unroll
        for (int m = 0; m < 4; m++)
#pragma unroll
            for (int n = 0; n < 2; n++) {
                acc[m][n] = mfma16(aF[m][0], bF[n][0], acc[m][n]);
                acc[m][n] = mfma16(aF[m][1], bF[n][1], acc[m][n]);
            }
        __builtin_amdgcn_s_setprio(0);
        __builtin_amdgcn_s_barrier();

        STG_WA(t2, cur);
#pragma unroll
        for (int n = 2; n < 4; n++) {
            bF[n][0] = *(const short8*)(Bb + n * 2048);
            bF[n][1] = *(const short8*)(Bb + n * 2048 + 64);
        }
        __builtin_amdgcn_s_setprio(1);
#pragma unroll
        for (int m = 0; m < 4; m++)
#pragma unroll
            for (int n = 2; n < 4; n++) {
                acc[m][n] = mfma16(aF[m][0], bF[n][0], acc[m][n]);
                acc[m][n] = mfma16(aF[m][1], bF[n][1], acc[m][n]);
            }
        __builtin_amdgcn_s_setprio(0);
        asm volatile("s_waitcnt vmcnt(2)" ::: "memory");
        __builtin_amdgcn_s_barrier();
    }
#undef STG_WA
#undef STG_WB

    const int rbase = by * 128 + wr * 64 + lh * 4;
    const int cbase = bx * 256 + wc * 64 + l15;
#pragma unroll
    for (int m = 0; m < 4; m++)
#pragma unroll
        for (int j = 0; j < 4; j++) {
            size_t ro = (size_t)(rbase + m * 16 + j) * 2048 + cbase;
#pragma unroll
            for (int n = 0; n < 4; n++)
                Of[ro + n * 16] = acc[m][n][j];
        }
}

// ---------------- flash attention (non-causal, GQA) ----------------
// R7-proven structure: grid (16 qtiles, 32 bh) x-major; block 256 = 4 waves;
// wave owns 32 q rows (2 groups sharing K/V frags); KVBLK=64 double-buffered;
// LDS 80KB -> 2 blocks/CU. RoPE-Q fused into Q load. exp2-domain softmax,
// defer-max THR=8, lane-local lsum reduced in epilogue.
// __launch_bounds__(256,2) — do NOT raise: min-waves 4 caps VGPR at 128 and
// spills the 64-reg accumulator (R8/R9: 455MB scratch writes, 4x slower).
__global__ __launch_bounds__(256, 2) void attn_kernel(const u16* __restrict__ Q,
                                                      const u16* __restrict__ Kg,
                                                      const u16* __restrict__ Vg,
                                                      const float* __restrict__ fc,
                                                      const float* __restrict__ fs,
                                                      u16* __restrict__ O) {
    __shared__ __align__(16) u16 Ks[2][8192];  // [buf][64 key][128 d] swizzled
    __shared__ __align__(16) u16 Vs[2][8192];  // [buf][128 d][64 s]  swizzled
    __shared__ __align__(16) u16 Ps[4][2048];  // per-wave [32 q][64 k] swizzled
    const int tid = threadIdx.x;
    const int w = tid >> 6, l = tid & 63;
    const int qt = blockIdx.x, bh = blockIdx.y;
    const int b = bh >> 4, h = bh & 15, h2 = h >> 1;
    const int l15 = l & 15, lh = l >> 4;

    char* KsB = (char*)&Ks[0][0];
    char* VsB = (char*)&Vs[0][0];
    char* PsB = (char*)&Ps[w][0];

    const char* Kbase = (const char*)Kg + (size_t)b * 2048 * 2048 + h2 * 256;
    const char* Vbase = (const char*)Vg + (size_t)(b * 8 + h2) * 128 * 4096;
    int krow[4], kcol[4], vrow[4], vcol[4];
#pragma unroll
    for (int c = 0; c < 4; c++) {
        int X = c * 4096 + tid * 16;
        krow[c] = X >> 8; kcol[c] = (X & 255) ^ ((krow[c] & 7) << 4);
        vrow[c] = X >> 7; vcol[c] = (X & 127) ^ ((vrow[c] & 7) << 4);
    }

#define STAGE(t, pb) do {                                               \
        const char* Kt = Kbase + (size_t)(t) * 131072;                  \
        const char* Vt = Vbase + (t) * 128;                             \
        char* kd = KsB + (pb) * 16384 + tid * 16;                       \
        char* vd = VsB + (pb) * 16384 + tid * 16;                       \
        _Pragma("unroll")                                               \
        for (int c = 0; c < 4; c++) {                                   \
            gload_lds16(Kt + krow[c] * 2048 + kcol[c], kd + c * 4096);  \
            gload_lds16(Vt + (size_t)vrow[c] * 4096 + vcol[c], vd + c * 4096); \
        }                                                               \
    } while (0)

    // Q fragments for both q-groups, RoPE applied in-register;
    // scale log2e/sqrt(128) folded into cos/sin
    const float OSC = 0.12751742987f;
    short8 qf0[4], qf1[4];
    {
        const int s0r = qt * 128 + w * 32 + l15;
        const int s1r = s0r + 16;
        const u16* qp0 = Q + ((size_t)(b * 2048 + s0r)) * 2048 + h * 128 + lh * 8;
        const u16* qp1 = Q + ((size_t)(b * 2048 + s1r)) * 2048 + h * 128 + lh * 8;
#pragma unroll
        for (int ks = 0; ks < 4; ks++) {
            qf0[ks] = rope8(*(const short8*)(qp0 + ks * 32),
                            &fc[s0r * 64 + ks * 16 + lh * 4],
                            &fs[s0r * 64 + ks * 16 + lh * 4], OSC);
            qf1[ks] = rope8(*(const short8*)(qp1 + ks * 32),
                            &fc[s1r * 64 + ks * 16 + lh * 4],
                            &fs[s1r * 64 + ks * 16 + lh * 4], OSC);
        }
    }

    const f32x4 fz = {0.f, 0.f, 0.f, 0.f};
    f32x4 o0[8], o1[8];
#pragma unroll
    for (int n = 0; n < 8; n++) { o0[n] = fz; o1[n] = fz; }
    float mrow0[4] = {-1e30f, -1e30f, -1e30f, -1e30f};
    float mrow1[4] = {-1e30f, -1e30f, -1e30f, -1e30f};
    float lsum0[4] = {0.f, 0.f, 0.f, 0.f};
    float lsum1[4] = {0.f, 0.f, 0.f, 0.f};

    STAGE(0, 0);

    for (int t = 0; t < 32; t++) {
        __syncthreads();                 // drains vmcnt(0): stage(t) landed
        const int pb = t & 1;
        if (t < 31) STAGE(t + 1, pb ^ 1);
        const char* kc = KsB + pb * 16384;
        const char* vc = VsB + pb * 16384;
        const int swz = (l15 & 7) << 4;

        // S = Q.K^T for both q-groups; K frags read ONCE
        f32x4 s0[4], s1[4];
#pragma unroll
        for (int ct = 0; ct < 4; ct++) {
            s0[ct] = fz; s1[ct] = fz;
#pragma unroll
            for (int ks = 0; ks < 4; ks++) {
                short8 kf = *(const short8*)(kc + ((ct * 16 + l15) << 8)
                                                + ((ks * 64 + lh * 16) ^ swz));
                s0[ct] = mfma16(qf0[ks], kf, s0[ct]);
                s1[ct] = mfma16(qf1[ks], kf, s1[ct]);
            }
        }

        // defer-max online softmax, both groups
        float pl0[4], pl1[4];
#pragma unroll
        for (int r = 0; r < 4; r++) {
            pl0[r] = fmaxf(fmaxf(s0[0][r], s0[1][r]), fmaxf(s0[2][r], s0[3][r]));
            pl1[r] = fmaxf(fmaxf(s1[0][r], s1[1][r]), fmaxf(s1[2][r], s1[3][r]));
        }
        bool grow = false;
#pragma unroll
        for (int r = 0; r < 4; r++)
            grow = grow || (pl0[r] > mrow0[r] + 8.f) || (pl1[r] > mrow1[r] + 8.f);
        if (__any(grow)) {
#pragma unroll
            for (int r = 0; r < 4; r++) {
                float mx = pl0[r];
                mx = fmaxf(mx, __shfl_xor(mx, 1));
                mx = fmaxf(mx, __shfl_xor(mx, 2));
                mx = fmaxf(mx, __shfl_xor(mx, 4));
                mx = fmaxf(mx, __shfl_xor(mx, 8));
                float mnew = fmaxf(mrow0[r], mx);
                float fsc = exp2f(mrow0[r] - mnew);
                mrow0[r] = mnew;
                lsum0[r] *= fsc;
#pragma unroll
                for (int n = 0; n < 8; n++) o0[n][r] *= fsc;
            }
#pragma unroll
            for (int r = 0; r < 4; r++) {
                float mx = pl1[r];
                mx = fmaxf(mx, __shfl_xor(mx, 1));
                mx = fmaxf(mx, __shfl_xor(mx, 2));
                mx = fmaxf(mx, __shfl_xor(mx, 4));
                mx = fmaxf(mx, __shfl_xor(mx, 8));
                float mnew = fmaxf(mrow1[r], mx);
                float fsc = exp2f(mrow1[r] - mnew);
                mrow1[r] = mnew;
                lsum1[r] *= fsc;
#pragma unroll
                for (int n = 0; n < 8; n++) o1[n][r] *= fsc;
            }
        }
        const int cb2 = l15 << 1;
#pragma unroll
        for (int r = 0; r < 4; r++) {
            float p0 = exp2f(s0[0][r] - mrow0[r]);
            float p1 = exp2f(s0[1][r] - mrow0[r]);
            float p2 = exp2f(s0[2][r] - mrow0[r]);
            float p3 = exp2f(s0[3][r] - mrow0[r]);
            lsum0[r] += (p0 + p1) + (p2 + p3);
            const int rw = lh * 4 + r;
            const int rb = rw << 7;
            const int sw2 = (rw & 7) << 4;
            *(u16*)(PsB + (rb + (( 0 + cb2) ^ sw2))) =
                (u16)((__float_as_uint(p0) + 0x8000u) >> 16);
            *(u16*)(PsB + (rb + ((32 + cb2) ^ sw2))) =
                (u16)((__float_as_uint(p1) + 0x8000u) >> 16);
            *(u16*)(PsB + (rb + ((64 + cb2) ^ sw2))) =
                (u16)((__float_as_uint(p2) + 0x8000u) >> 16);
            *(u16*)(PsB + (rb + ((96 + cb2) ^ sw2))) =
                (u16)((__float_as_uint(p3) + 0x8000u) >> 16);
        }
#pragma unroll
        for (int r = 0; r < 4; r++) {
            float p0 = exp2f(s1[0][r] - mrow1[r]);
            float p1 = exp2f(s1[1][r] - mrow1[r]);
            float p2 = exp2f(s1[2][r] - mrow1[r]);
            float p3 = exp2f(s1[3][r] - mrow1[r]);
            lsum1[r] += (p0 + p1) + (p2 + p3);
            const int rw = 16 + lh * 4 + r;
            const int rb = rw << 7;
            const int sw2 = (rw & 7) << 4;
            *(u16*)(PsB + (rb + (( 0 + cb2) ^ sw2))) =
                (u16)((__float_as_uint(p0) + 0x8000u) >> 16);
            *(u16*)(PsB + (rb + ((32 + cb2) ^ sw2))) =
                (u16)((__float_as_uint(p1) + 0x8000u) >> 16);
            *(u16*)(PsB + (rb + ((64 + cb2) ^ sw2))) =
                (u16)((__float_as_uint(p2) + 0x8000u) >> 16);
            *(u16*)(PsB + (rb + ((96 + cb2) ^ sw2))) =
                (u16)((__float_as_uint(p3) + 0x8000u) >> 16);
        }

        // PV for both groups; V frags read ONCE
#pragma unroll
        for (int ks2 = 0; ks2 < 2; ks2++) {
            short8 pf0 = *(const short8*)(PsB + ((l15 << 7)
                                + ((ks2 * 64 + lh * 16) ^ swz)));
            short8 pf1 = *(const short8*)(PsB + (((16 + l15) << 7)
                                + ((ks2 * 64 + lh * 16) ^ swz)));
#pragma unroll
            for (int n = 0; n < 8; n++) {
                short8 vf = *(const short8*)(vc + (((n * 16 + l15) << 7)
                                                  + ((ks2 * 64 + lh * 16) ^ swz)));
                o0[n] = mfma16(pf0, vf, o0[n]);
                o1[n] = mfma16(pf1, vf, o1[n]);
            }
        }
    }

    // epilogue: normalize and store
    const int q0 = qt * 128 + w * 32;
    const size_t ob0 = ((size_t)(b * 2048 + q0 + lh * 4)) * 2048 + h * 128 + l15;
#pragma unroll
    for (int r = 0; r < 4; r++) {
        float ls = lsum0[r];
        ls += __shfl_xor(ls, 1);
        ls += __shfl_xor(ls, 2);
        ls += __shfl_xor(ls, 4);
        ls += __shfl_xor(ls, 8);
        float li = 1.0f / ls;
#pragma unroll
        for (int n = 0; n < 8; n++)
            O[ob0 + (size_t)r * 2048 + n * 16] = f2bf(o0[n][r] * li);
    }
    const size_t ob1 = ob0 + (size_t)16 * 2048;
#pragma unroll
    for (int r = 0; r < 4; r++) {
        float ls = lsum1[r];
        ls += __shfl_xor(ls, 1);
        ls += __shfl_xor(ls, 2);
        ls += __shfl_xor(ls, 4);
        ls += __shfl_xor(ls, 8);
        float li = 1.0f / ls;
#pragma unroll
        for (int n = 0; n < 8; n++)
            O[ob1 + (size_t)r * 2048 + n * 16] = f2bf(o1[n][r] * li);
    }
#undef STAGE
}

// ---------------- launch ----------------
extern "C" void kernel_launch(void* const* d_in, const int* in_sizes, int n_in,
                              void* d_out, int out_size, void* d_ws, size_t ws_size,
                              hipStream_t stream) {
    const float* x  = (const float*)d_in[0];
    const float* Wq = (const float*)d_in[1];
    const float* Wk = (const float*)d_in[2];
    const float* Wv = (const float*)d_in[3];
    const float* Wo = (const float*)d_in[4];
    const float* fc = (const float*)d_in[5];
    const float* fs = (const float*)d_in[6];
    float* out = (float*)d_out;

    uint8_t* ws = (uint8_t*)d_ws;
    u16* xb   = (u16*)(ws + 0);          // 16.8 MB  (attn-out alias)
    u16* wqkv = (u16*)(ws + 16777216);   // 16.8 MB: wqT|wkT|wvT contiguous
    u16* wqT  = (u16*)(ws + 16777216);
    u16* wkT  = (u16*)(ws + 25165824);
    u16* wvT  = (u16*)(ws + 29360128);
    u16* woT  = (u16*)(ws + 33554432);   // 8.4 MB
    u16* qb   = (u16*)(ws + 41943040);   // 16.8 MB
    u16* kb   = (u16*)(ws + 58720256);   // 8.4 MB
    u16* vT   = (u16*)(ws + 67108864);   // 8.4 MB   total 75.5 MB
    u16* ao   = xb;                      // alias: x_bf16 dead after QKV gemm

    cvt_x<<<dim3(8192), dim3(256), 0, stream>>>(x, xb, 2097152);
    transpose_cvt4<<<dim3(32, 32, 4), dim3(256), 0, stream>>>(Wq, Wk, Wv, Wo,
                                                              wqT, wkT, wvT, woT);

    gemm_qkv2<<<dim3(512), dim3(512), 0, stream>>>(xb, wqkv, qb, kb, vT);

    rope_kernel<<<dim3(8192), dim3(256), 0, stream>>>(kb, fc, fs, 8, 9, 2097152, 1.0f);

    attn_kernel<<<dim3(16, 32), dim3(256), 0, stream>>>(qb, kb, vT, fc, fs, ao);

    gemm_wo8<<<dim3(256), dim3(512), 0, stream>>>(ao, woT, out);
}

// Round 15
// 228.324 us; speedup vs baseline: 1.0799x; 1.0799x over previous
//
#include <hip/hip_runtime.h>
#include <stdint.h>

#define DI __device__ __forceinline__

typedef unsigned short u16;
typedef unsigned int   u32;
typedef __attribute__((ext_vector_type(8))) short short8;
typedef __attribute__((ext_vector_type(4))) float f32x4;

// ---- constants (problem shape hardcoded) ----
// B=2, S=2048, HID=2048, HQ=16, HKV=8, D=128

DI u16 f2bf(float f) {
    u32 u = __float_as_uint(f);
    u32 r = u + 0x7fff + ((u >> 16) & 1);   // RNE
    return (u16)(r >> 16);
}
DI u32 pk2bf(float a, float b) {
    return (u32)f2bf(a) | ((u32)f2bf(b) << 16);
}
DI float bf2f(u16 h) { return __uint_as_float(((u32)h) << 16); }

DI f32x4 mfma16(short8 a, short8 b, f32x4 c) {
    return __builtin_amdgcn_mfma_f32_16x16x32_bf16(a, b, c, 0, 0, 0);
}

DI void gload_lds16(const void* g, void* l) {
    __builtin_amdgcn_global_load_lds(
        (const __attribute__((address_space(1))) void*)g,
        (__attribute__((address_space(3))) void*)l, 16, 0, 0);
}

// rotate 4 bf16 (re,im) pairs by cos/sin (float4), scale folded into c/s
DI short8 rope8(short8 raw, const float* cp, const float* sp, float osc) {
    float4 c4 = *(const float4*)cp;
    float4 s4 = *(const float4*)sp;
    u32* rp = (u32*)&raw;
#pragma unroll
    for (int p = 0; p < 4; p++) {
        u32 v = rp[p];
        float re = __uint_as_float(v << 16);
        float im = __uint_as_float(v & 0xffff0000u);
        float cc = ((const float*)&c4)[p] * osc;
        float ss = ((const float*)&s4)[p] * osc;
        rp[p] = pk2bf(re * cc - im * ss, re * ss + im * cc);
    }
    return raw;
}

// ---------------- convert x f32 -> bf16 ----------------
__global__ __launch_bounds__(256) void cvt_x(const float* __restrict__ x,
                                             u16* __restrict__ o, int n4) {
    int i = blockIdx.x * 256 + threadIdx.x;
    if (i >= n4) return;
    float4 v = *(const float4*)(x + (size_t)i * 4);
    uint2 p; p.x = pk2bf(v.x, v.y); p.y = pk2bf(v.z, v.w);
    *(uint2*)(o + (size_t)i * 4) = p;
}

// ---------------- all 4 weights: W [K][N] f32 -> WT [N][K] bf16, one launch ----
__global__ __launch_bounds__(256) void transpose_cvt4(const float* __restrict__ W0,
                                                      const float* __restrict__ W1,
                                                      const float* __restrict__ W2,
                                                      const float* __restrict__ W3,
                                                      u16* __restrict__ D0,
                                                      u16* __restrict__ D1,
                                                      u16* __restrict__ D2,
                                                      u16* __restrict__ D3) {
    const float* W; u16* D; int N;
    switch (blockIdx.z) {
        case 0:  W = W0; D = D0; N = 2048; break;
        case 1:  W = W1; D = D1; N = 1024; break;
        case 2:  W = W2; D = D2; N = 1024; break;
        default: W = W3; D = D3; N = 2048; break;
    }
    if ((int)blockIdx.x >= (N >> 6)) return;
    const int K = 2048;
    __shared__ u16 tl[64][65];
    int tx = threadIdx.x & 15, ty = threadIdx.x >> 4;
    int tc = blockIdx.x * 64, tr = blockIdx.y * 64;
#pragma unroll
    for (int i = 0; i < 4; i++) {
        int r = tr + ty + i * 16;
        float4 v = *(const float4*)&W[(size_t)r * N + tc + tx * 4];
        tl[tx*4+0][ty+i*16] = f2bf(v.x);
        tl[tx*4+1][ty+i*16] = f2bf(v.y);
        tl[tx*4+2][ty+i*16] = f2bf(v.z);
        tl[tx*4+3][ty+i*16] = f2bf(v.w);
    }
    __syncthreads();
#pragma unroll
    for (int i = 0; i < 4; i++) {
        int n = tc + ty + i * 16;
        uint2 p;
        p.x = (u32)tl[ty+i*16][tx*4+0] | ((u32)tl[ty+i*16][tx*4+1] << 16);
        p.y = (u32)tl[ty+i*16][tx*4+2] | ((u32)tl[ty+i*16][tx*4+3] << 16);
        *(uint2*)&D[(size_t)n * K + tr + tx * 4] = p;
    }
}

// ---------------- 8-phase 256^2 QKV GEMM (T2+T3+T4+T5) --------
// K-RoPE fused into the K epilogue: feature pairs (2j,2j+1) live in adjacent
// lanes (parity(feat)=parity(l15)), so rotation = shfl_xor(acc,1) + 2 VALU,
// applied to f32 acc BEFORE bf16 rounding.
__global__ __launch_bounds__(512) void gemm_qkv8(const u16* __restrict__ A,
                                                 const u16* __restrict__ BT,
                                                 const float* __restrict__ fc,
                                                 const float* __restrict__ fs,
                                                 u16* __restrict__ Qo,
                                                 u16* __restrict__ Ko,
                                                 u16* __restrict__ Vo) {
    __shared__ __align__(16) u16 SM[65536];   // 128 KB
    char* smb = (char*)SM;
    const int tid = threadIdx.x;
    const int w = tid >> 6, l = tid & 63;
    const int l15 = l & 15, lh = l >> 4;
    const int wr = w >> 2, wc = w & 3;

    const int bid = blockIdx.x;
    const int sw = (bid & 7) * 32 + (bid >> 3);
    const int bx = sw & 15, by = sw >> 4;

    const char* Ag = (const char*)A  + (size_t)(by * 256) * 4096;
    const char* Bg = (const char*)BT + (size_t)(bx * 256) * 4096;

    const int r0 = tid >> 3;
    const int c0 = ((tid & 7) << 4) ^ (((tid >> 5) & 1) << 5);
    const int wb = w << 10;

#define STG_A(tt, bb, hh) do {                                              \
        const char* s_ = Ag + (size_t)((hh) * 128 + r0) * 4096 + (tt) * 128 + c0; \
        char* d_ = smb + (bb) * 65536 + (hh) * 16384 + wb;                  \
        gload_lds16(s_, d_);                                                \
        gload_lds16(s_ + (size_t)64 * 4096, d_ + 8192);                     \
    } while (0)
#define STG_B(tt, bb, hh) do {                                              \
        const char* s_ = Bg + (size_t)((hh) * 128 + r0) * 4096 + (tt) * 128 + c0; \
        char* d_ = smb + (bb) * 65536 + 32768 + (hh) * 16384 + wb;          \
        gload_lds16(s_, d_);                                                \
        gload_lds16(s_ + (size_t)64 * 4096, d_ + 8192);                     \
    } while (0)

    const int aoff = l15 * 128 + ((lh * 16) ^ (((l15 >> 2) & 1) << 5));

    const f32x4 fz = {0.f, 0.f, 0.f, 0.f};
    f32x4 acc[8][4];
#pragma unroll
    for (int m = 0; m < 8; m++)
#pragma unroll
        for (int n = 0; n < 4; n++) acc[m][n] = fz;

    STG_A(0, 0, 0); STG_A(0, 0, 1); STG_B(0, 0, 0); STG_B(0, 0, 1);
    STG_A(1, 1, 0);
    asm volatile("s_waitcnt vmcnt(2)" ::: "memory");
    __builtin_amdgcn_s_barrier();

    for (int t = 0; t < 32; ++t) {
        const int cur = t & 1;
        const int t1 = t + 1 < 32 ? t + 1 : 31;
        const int t2 = t + 2 < 32 ? t + 2 : 31;
        const char* Ab = smb + cur * 65536 + wr * 16384 + aoff;
        const char* Bb = smb + cur * 65536 + 32768 + (wc >> 1) * 16384
                         + (wc & 1) * 8192 + aoff;
        short8 aF[4][2], bF[4][2];

        STG_A(t1, cur ^ 1, 1);
#pragma unroll
        for (int m = 0; m < 4; m++) {
            aF[m][0] = *(const short8*)(Ab + m * 2048);
            aF[m][1] = *(const short8*)(Ab + m * 2048 + 64);
        }
#pragma unroll
        for (int n = 0; n < 2; n++) {
            bF[n][0] = *(const short8*)(Bb + n * 2048);
            bF[n][1] = *(const short8*)(Bb + n * 2048 + 64);
        }
        __builtin_amdgcn_s_setprio(1);
#pragma unroll
        for (int m = 0; m < 4; m++)
#pragma unroll
            for (int n = 0; n < 2; n++) {
                acc[m][n] = mfma16(aF[m][0], bF[n][0], acc[m][n]);
                acc[m][n] = mfma16(aF[m][1], bF[n][1], acc[m][n]);
            }
        __builtin_amdgcn_s_setprio(0);
        __builtin_amdgcn_s_barrier();

        STG_B(t1, cur ^ 1, 0);
#pragma unroll
        for (int n = 2; n < 4; n++) {
            bF[n][0] = *(const short8*)(Bb + n * 2048);
            bF[n][1] = *(const short8*)(Bb + n * 2048 + 64);
        }
        __builtin_amdgcn_s_setprio(1);
#pragma unroll
        for (int m = 0; m < 4; m++)
#pragma unroll
            for (int n = 2; n < 4; n++) {
                acc[m][n] = mfma16(aF[m][0], bF[n][0], acc[m][n]);
                acc[m][n] = mfma16(aF[m][1], bF[n][1], acc[m][n]);
            }
        __builtin_amdgcn_s_setprio(0);
        __builtin_amdgcn_s_barrier();

        STG_B(t1, cur ^ 1, 1);
#pragma unroll
        for (int m = 0; m < 4; m++) {
            aF[m][0] = *(const short8*)(Ab + (m + 4) * 2048);
            aF[m][1] = *(const short8*)(Ab + (m + 4) * 2048 + 64);
        }
        __builtin_amdgcn_s_setprio(1);
#pragma unroll
        for (int m = 0; m < 4; m++)
#pragma unroll
            for (int n = 0; n < 2; n++) {
                acc[m + 4][n] = mfma16(aF[m][0], bF[n][0], acc[m + 4][n]);
                acc[m + 4][n] = mfma16(aF[m][1], bF[n][1], acc[m + 4][n]);
            }
        __builtin_amdgcn_s_setprio(0);
        __builtin_amdgcn_s_barrier();

        STG_A(t2, cur, 0);
        __builtin_amdgcn_s_setprio(1);
#pragma unroll
        for (int m = 0; m < 4; m++)
#pragma unroll
            for (int n = 2; n < 4; n++) {
                acc[m + 4][n] = mfma16(aF[m][0], bF[n][0], acc[m + 4][n]);
                acc[m + 4][n] = mfma16(aF[m][1], bF[n][1], acc[m + 4][n]);
            }
        __builtin_amdgcn_s_setprio(0);
        asm volatile("s_waitcnt vmcnt(2)" ::: "memory");
        __builtin_amdgcn_s_barrier();
    }
#undef STG_A
#undef STG_B

    const int rbase = by * 256 + wr * 128 + lh * 4;
    const int cbase = bx * 256 + wc * 64 + l15;
    if (bx < 8) {                       // Q [tok][2048]
#pragma unroll
        for (int m = 0; m < 8; m++)
#pragma unroll
            for (int j = 0; j < 4; j++) {
                size_t ro = (size_t)(rbase + m * 16 + j) * 2048 + cbase;
#pragma unroll
                for (int n = 0; n < 4; n++)
                    Qo[ro + n * 16] = f2bf(acc[m][n][j]);
            }
    } else if (bx < 12) {               // K [tok][1024], RoPE fused
        const int ck = cbase - 2048;
        const bool odd = (l15 & 1) != 0;
#pragma unroll
        for (int m = 0; m < 8; m++)
#pragma unroll
            for (int j = 0; j < 4; j++) {
                const int tok = rbase + m * 16 + j;
                const int s = tok & 2047;
                const float* fcb = fc + s * 64;
                const float* fsb = fs + s * 64;
                size_t ro = (size_t)tok * 1024 + ck;
#pragma unroll
                for (int n = 0; n < 4; n++) {
                    const int j2 = ((ck + n * 16) & 127) >> 1;
                    float own = acc[m][n][j];
                    float prt = __shfl_xor(own, 1);
                    float c = fcb[j2], sn = fsb[j2];
                    float out = odd ? (prt * sn + own * c)
                                    : (own * c - prt * sn);
                    Ko[ro + n * 16] = f2bf(out);
                }
            }
    } else {                            // V -> V^T[b][h2][d][s]
#pragma unroll
        for (int m = 0; m < 8; m++)
#pragma unroll
            for (int n = 0; n < 4; n++) {
                int tok = rbase + m * 16;
                int c = cbase + n * 16 - 3072;
                int bb2 = tok >> 11, ss = tok & 2047;
                int h2 = c >> 7, d = c & 127;
                uint2 v;
                v.x = pk2bf(acc[m][n][0], acc[m][n][1]);
                v.y = pk2bf(acc[m][n][2], acc[m][n][3]);
                *(uint2*)(Vo + (size_t)((bb2 * 8 + h2) * 128 + d) * 2048 + ss) = v;
            }
    }
}

// ---------------- Wo GEMM, 2-phase counted-vmcnt template (BM=128 BN=256) ----
__global__ __launch_bounds__(512) void gemm_wo8(const u16* __restrict__ A,
                                                const u16* __restrict__ BT,
                                                float* __restrict__ Of) {
    __shared__ __align__(16) u16 SM[49152];   // 96 KB
    char* smb = (char*)SM;
    const int tid = threadIdx.x;
    const int w = tid >> 6, l = tid & 63;
    const int l15 = l & 15, lh = l >> 4;
    const int wr = w >> 2, wc = w & 3;        // 2M x 4N

    const int bid = blockIdx.x;
    const int sw = (bid & 7) * 32 + (bid >> 3);
    const int bx = sw & 7, by = sw >> 3;      // bx: 8 N-tiles, by: 32 M-tiles

    const char* Ag = (const char*)A  + (size_t)(by * 128) * 4096;
    const char* Bg = (const char*)BT + (size_t)(bx * 256) * 4096;

    const int r0 = tid >> 3;                                   // 64 rows/issue
    const int c0 = ((tid & 7) << 4) ^ (((tid >> 5) & 1) << 5); // src pre-swizzle
    const int wb = w << 10;

#define STG_WA(tt, bb) do {                                                 \
        const char* s_ = Ag + (size_t)r0 * 4096 + (tt) * 128 + c0;          \
        char* d_ = smb + (bb) * 49152 + wb;                                 \
        gload_lds16(s_, d_);                                                \
        gload_lds16(s_ + (size_t)64 * 4096, d_ + 8192);                     \
    } while (0)
#define STG_WB(tt, bb) do {                                                 \
        const char* s_ = Bg + (size_t)r0 * 4096 + (tt) * 128 + c0;          \
        char* d_ = smb + (bb) * 49152 + 16384 + wb;                         \
        gload_lds16(s_, d_);                                                \
        gload_lds16(s_ + (size_t)64 * 4096, d_ + 8192);                     \
        gload_lds16(s_ + (size_t)128 * 4096, d_ + 16384);                   \
        gload_lds16(s_ + (size_t)192 * 4096, d_ + 24576);                   \
    } while (0)

    const int aoff = l15 * 128 + ((lh * 16) ^ (((l15 >> 2) & 1) << 5));

    const f32x4 fz = {0.f, 0.f, 0.f, 0.f};
    f32x4 acc[4][4];
#pragma unroll
    for (int m = 0; m < 4; m++)
#pragma unroll
        for (int n = 0; n < 4; n++) acc[m][n] = fz;

    STG_WA(0, 0); STG_WB(0, 0);
    STG_WA(1, 1);
    asm volatile("s_waitcnt vmcnt(2)" ::: "memory");
    __builtin_amdgcn_s_barrier();

    for (int t = 0; t < 32; ++t) {
        const int cur = t & 1;
        const int t1 = t + 1 < 32 ? t + 1 : 31;
        const int t2 = t + 2 < 32 ? t + 2 : 31;
        const char* Ab = smb + cur * 49152 + wr * 8192 + aoff;
        const char* Bb = smb + cur * 49152 + 16384 + wc * 8192 + aoff;
        short8 aF[4][2], bF[4][2];

        STG_WB(t1, cur ^ 1);
#pragma unroll
        for (int m = 0; m < 4; m++) {
            aF[m][0] = *(const short8*)(Ab + m * 2048);
            aF[m][1] = *(const short8*)(Ab + m * 2048 + 64);
        }
#pragma unroll
        for (int n = 0; n < 2; n++) {
            bF[n][0] = *(const short8*)(Bb + n * 2048);
            bF[n][1] = *(const short8*)(Bb + n * 2048 + 64);
        }
        __builtin_amdgcn_s_setprio(1);
#pragma unroll
        for (int m = 0; m < 4; m++)
#pragma unroll
            for (int n = 0; n < 2; n++) {
                acc[m][n] = mfma16(aF[m][0], bF[n][0], acc[m][n]);
                acc[m][n] = mfma16(aF[m][1], bF[n][1], acc[m][n]);
            }
        __builtin_amdgcn_s_setprio(0);
        __builtin_amdgcn_s_barrier();

        STG_WA(t2, cur);
#pragma unroll
        for (int n = 2; n < 4; n++) {
            bF[n][0] = *(const short8*)(Bb + n * 2048);
            bF[n][1] = *(const short8*)(Bb + n * 2048 + 64);
        }
        __builtin_amdgcn_s_setprio(1);
#pragma unroll
        for (int m = 0; m < 4; m++)
#pragma unroll
            for (int n = 2; n < 4; n++) {
                acc[m][n] = mfma16(aF[m][0], bF[n][0], acc[m][n]);
                acc[m][n] = mfma16(aF[m][1], bF[n][1], acc[m][n]);
            }
        __builtin_amdgcn_s_setprio(0);
        asm volatile("s_waitcnt vmcnt(2)" ::: "memory");
        __builtin_amdgcn_s_barrier();
    }
#undef STG_WA
#undef STG_WB

    const int rbase = by * 128 + wr * 64 + lh * 4;
    const int cbase = bx * 256 + wc * 64 + l15;
#pragma unroll
    for (int m = 0; m < 4; m++)
#pragma unroll
        for (int j = 0; j < 4; j++) {
            size_t ro = (size_t)(rbase + m * 16 + j) * 2048 + cbase;
#pragma unroll
            for (int n = 0; n < 4; n++)
                Of[ro + n * 16] = acc[m][n][j];
        }
}

// ---------------- flash attention (non-causal, GQA) ----------------
// R7-proven structure: grid (16 qtiles, 32 bh) x-major; block 256 = 4 waves;
// wave owns 32 q rows (2 groups sharing K/V frags); KVBLK=64 double-buffered;
// LDS 80KB -> 2 blocks/CU. RoPE-Q fused into Q load. exp2-domain softmax,
// defer-max THR=8, lane-local lsum reduced in epilogue.
// __launch_bounds__(256,2) — do NOT raise: min-waves 4 caps VGPR at 128 and
// spills the 64-reg accumulator (R8/R9: 455MB scratch writes, 4x slower).
__global__ __launch_bounds__(256, 2) void attn_kernel(const u16* __restrict__ Q,
                                                      const u16* __restrict__ Kg,
                                                      const u16* __restrict__ Vg,
                                                      const float* __restrict__ fc,
                                                      const float* __restrict__ fs,
                                                      u16* __restrict__ O) {
    __shared__ __align__(16) u16 Ks[2][8192];  // [buf][64 key][128 d] swizzled
    __shared__ __align__(16) u16 Vs[2][8192];  // [buf][128 d][64 s]  swizzled
    __shared__ __align__(16) u16 Ps[4][2048];  // per-wave [32 q][64 k] swizzled
    const int tid = threadIdx.x;
    const int w = tid >> 6, l = tid & 63;
    const int qt = blockIdx.x, bh = blockIdx.y;
    const int b = bh >> 4, h = bh & 15, h2 = h >> 1;
    const int l15 = l & 15, lh = l >> 4;

    char* KsB = (char*)&Ks[0][0];
    char* VsB = (char*)&Vs[0][0];
    char* PsB = (char*)&Ps[w][0];

    const char* Kbase = (const char*)Kg + (size_t)b * 2048 * 2048 + h2 * 256;
    const char* Vbase = (const char*)Vg + (size_t)(b * 8 + h2) * 128 * 4096;
    int krow[4], kcol[4], vrow[4], vcol[4];
#pragma unroll
    for (int c = 0; c < 4; c++) {
        int X = c * 4096 + tid * 16;
        krow[c] = X >> 8; kcol[c] = (X & 255) ^ ((krow[c] & 7) << 4);
        vrow[c] = X >> 7; vcol[c] = (X & 127) ^ ((vrow[c] & 7) << 4);
    }

#define STAGE(t, pb) do {                                               \
        const char* Kt = Kbase + (size_t)(t) * 131072;                  \
        const char* Vt = Vbase + (t) * 128;                             \
        char* kd = KsB + (pb) * 16384 + tid * 16;                       \
        char* vd = VsB + (pb) * 16384 + tid * 16;                       \
        _Pragma("unroll")                                               \
        for (int c = 0; c < 4; c++) {                                   \
            gload_lds16(Kt + krow[c] * 2048 + kcol[c], kd + c * 4096);  \
            gload_lds16(Vt + (size_t)vrow[c] * 4096 + vcol[c], vd + c * 4096); \
        }                                                               \
    } while (0)

    // Q fragments for both q-groups, RoPE applied in-register;
    // scale log2e/sqrt(128) folded into cos/sin
    const float OSC = 0.12751742987f;
    short8 qf0[4], qf1[4];
    {
        const int s0r = qt * 128 + w * 32 + l15;
        const int s1r = s0r + 16;
        const u16* qp0 = Q + ((size_t)(b * 2048 + s0r)) * 2048 + h * 128 + lh * 8;
        const u16* qp1 = Q + ((size_t)(b * 2048 + s1r)) * 2048 + h * 128 + lh * 8;
#pragma unroll
        for (int ks = 0; ks < 4; ks++) {
            qf0[ks] = rope8(*(const short8*)(qp0 + ks * 32),
                            &fc[s0r * 64 + ks * 16 + lh * 4],
                            &fs[s0r * 64 + ks * 16 + lh * 4], OSC);
            qf1[ks] = rope8(*(const short8*)(qp1 + ks * 32),
                            &fc[s1r * 64 + ks * 16 + lh * 4],
                            &fs[s1r * 64 + ks * 16 + lh * 4], OSC);
        }
    }

    const f32x4 fz = {0.f, 0.f, 0.f, 0.f};
    f32x4 o0[8], o1[8];
#pragma unroll
    for (int n = 0; n < 8; n++) { o0[n] = fz; o1[n] = fz; }
    float mrow0[4] = {-1e30f, -1e30f, -1e30f, -1e30f};
    float mrow1[4] = {-1e30f, -1e30f, -1e30f, -1e30f};
    float lsum0[4] = {0.f, 0.f, 0.f, 0.f};
    float lsum1[4] = {0.f, 0.f, 0.f, 0.f};

    STAGE(0, 0);

    for (int t = 0; t < 32; t++) {
        __syncthreads();                 // drains vmcnt(0): stage(t) landed
        const int pb = t & 1;
        if (t < 31) STAGE(t + 1, pb ^ 1);
        const char* kc = KsB + pb * 16384;
        const char* vc = VsB + pb * 16384;
        const int swz = (l15 & 7) << 4;

        // S = Q.K^T for both q-groups; K frags read ONCE
        f32x4 s0[4], s1[4];
#pragma unroll
        for (int ct = 0; ct < 4; ct++) {
            s0[ct] = fz; s1[ct] = fz;
#pragma unroll
            for (int ks = 0; ks < 4; ks++) {
                short8 kf = *(const short8*)(kc + ((ct * 16 + l15) << 8)
                                                + ((ks * 64 + lh * 16) ^ swz));
                s0[ct] = mfma16(qf0[ks], kf, s0[ct]);
                s1[ct] = mfma16(qf1[ks], kf, s1[ct]);
            }
        }

        // defer-max online softmax, both groups
        float pl0[4], pl1[4];
#pragma unroll
        for (int r = 0; r < 4; r++) {
            pl0[r] = fmaxf(fmaxf(s0[0][r], s0[1][r]), fmaxf(s0[2][r], s0[3][r]));
            pl1[r] = fmaxf(fmaxf(s1[0][r], s1[1][r]), fmaxf(s1[2][r], s1[3][r]));
        }
        bool grow = false;
#pragma unroll
        for (int r = 0; r < 4; r++)
            grow = grow || (pl0[r] > mrow0[r] + 8.f) || (pl1[r] > mrow1[r] + 8.f);
        if (__any(grow)) {
#pragma unroll
            for (int r = 0; r < 4; r++) {
                float mx = pl0[r];
                mx = fmaxf(mx, __shfl_xor(mx, 1));
                mx = fmaxf(mx, __shfl_xor(mx, 2));
                mx = fmaxf(mx, __shfl_xor(mx, 4));
                mx = fmaxf(mx, __shfl_xor(mx, 8));
                float mnew = fmaxf(mrow0[r], mx);
                float fsc = exp2f(mrow0[r] - mnew);
                mrow0[r] = mnew;
                lsum0[r] *= fsc;
#pragma unroll
                for (int n = 0; n < 8; n++) o0[n][r] *= fsc;
            }
#pragma unroll
            for (int r = 0; r < 4; r++) {
                float mx = pl1[r];
                mx = fmaxf(mx, __shfl_xor(mx, 1));
                mx = fmaxf(mx, __shfl_xor(mx, 2));
                mx = fmaxf(mx, __shfl_xor(mx, 4));
                mx = fmaxf(mx, __shfl_xor(mx, 8));
                float mnew = fmaxf(mrow1[r], mx);
                float fsc = exp2f(mrow1[r] - mnew);
                mrow1[r] = mnew;
                lsum1[r] *= fsc;
#pragma unroll
                for (int n = 0; n < 8; n++) o1[n][r] *= fsc;
            }
        }
        const int cb2 = l15 << 1;
#pragma unroll
        for (int r = 0; r < 4; r++) {
            float p0 = exp2f(s0[0][r] - mrow0[r]);
            float p1 = exp2f(s0[1][r] - mrow0[r]);
            float p2 = exp2f(s0[2][r] - mrow0[r]);
            float p3 = exp2f(s0[3][r] - mrow0[r]);
            lsum0[r] += (p0 + p1) + (p2 + p3);
            const int rw = lh * 4 + r;
            const int rb = rw << 7;
            const int sw2 = (rw & 7) << 4;
            *(u16*)(PsB + (rb + (( 0 + cb2) ^ sw2))) =
                (u16)((__float_as_uint(p0) + 0x8000u) >> 16);
            *(u16*)(PsB + (rb + ((32 + cb2) ^ sw2))) =
                (u16)((__float_as_uint(p1) + 0x8000u) >> 16);
            *(u16*)(PsB + (rb + ((64 + cb2) ^ sw2))) =
                (u16)((__float_as_uint(p2) + 0x8000u) >> 16);
            *(u16*)(PsB + (rb + ((96 + cb2) ^ sw2))) =
                (u16)((__float_as_uint(p3) + 0x8000u) >> 16);
        }
#pragma unroll
        for (int r = 0; r < 4; r++) {
            float p0 = exp2f(s1[0][r] - mrow1[r]);
            float p1 = exp2f(s1[1][r] - mrow1[r]);
            float p2 = exp2f(s1[2][r] - mrow1[r]);
            float p3 = exp2f(s1[3][r] - mrow1[r]);
            lsum1[r] += (p0 + p1) + (p2 + p3);
            const int rw = 16 + lh * 4 + r;
            const int rb = rw << 7;
            const int sw2 = (rw & 7) << 4;
            *(u16*)(PsB + (rb + (( 0 + cb2) ^ sw2))) =
                (u16)((__float_as_uint(p0) + 0x8000u) >> 16);
            *(u16*)(PsB + (rb + ((32 + cb2) ^ sw2))) =
                (u16)((__float_as_uint(p1) + 0x8000u) >> 16);
            *(u16*)(PsB + (rb + ((64 + cb2) ^ sw2))) =
                (u16)((__float_as_uint(p2) + 0x8000u) >> 16);
            *(u16*)(PsB + (rb + ((96 + cb2) ^ sw2))) =
                (u16)((__float_as_uint(p3) + 0x8000u) >> 16);
        }

        // PV for both groups; V frags read ONCE
#pragma unroll
        for (int ks2 = 0; ks2 < 2; ks2++) {
            short8 pf0 = *(const short8*)(PsB + ((l15 << 7)
                                + ((ks2 * 64 + lh * 16) ^ swz)));
            short8 pf1 = *(const short8*)(PsB + (((16 + l15) << 7)
                                + ((ks2 * 64 + lh * 16) ^ swz)));
#pragma unroll
            for (int n = 0; n < 8; n++) {
                short8 vf = *(const short8*)(vc + (((n * 16 + l15) << 7)
                                                  + ((ks2 * 64 + lh * 16) ^ swz)));
                o0[n] = mfma16(pf0, vf, o0[n]);
                o1[n] = mfma16(pf1, vf, o1[n]);
            }
        }
    }

    // epilogue: normalize and store
    const int q0 = qt * 128 + w * 32;
    const size_t ob0 = ((size_t)(b * 2048 + q0 + lh * 4)) * 2048 + h * 128 + l15;
#pragma unroll
    for (int r = 0; r < 4; r++) {
        float ls = lsum0[r];
        ls += __shfl_xor(ls, 1);
        ls += __shfl_xor(ls, 2);
        ls += __shfl_xor(ls, 4);
        ls += __shfl_xor(ls, 8);
        float li = 1.0f / ls;
#pragma unroll
        for (int n = 0; n < 8; n++)
            O[ob0 + (size_t)r * 2048 + n * 16] = f2bf(o0[n][r] * li);
    }
    const size_t ob1 = ob0 + (size_t)16 * 2048;
#pragma unroll
    for (int r = 0; r < 4; r++) {
        float ls = lsum1[r];
        ls += __shfl_xor(ls, 1);
        ls += __shfl_xor(ls, 2);
        ls += __shfl_xor(ls, 4);
        ls += __shfl_xor(ls, 8);
        float li = 1.0f / ls;
#pragma unroll
        for (int n = 0; n < 8; n++)
            O[ob1 + (size_t)r * 2048 + n * 16] = f2bf(o1[n][r] * li);
    }
#undef STAGE
}

// ---------------- launch ----------------
extern "C" void kernel_launch(void* const* d_in, const int* in_sizes, int n_in,
                              void* d_out, int out_size, void* d_ws, size_t ws_size,
                              hipStream_t stream) {
    const float* x  = (const float*)d_in[0];
    const float* Wq = (const float*)d_in[1];
    const float* Wk = (const float*)d_in[2];
    const float* Wv = (const float*)d_in[3];
    const float* Wo = (const float*)d_in[4];
    const float* fc = (const float*)d_in[5];
    const float* fs = (const float*)d_in[6];
    float* out = (float*)d_out;

    uint8_t* ws = (uint8_t*)d_ws;
    u16* xb   = (u16*)(ws + 0);          // 16.8 MB  (attn-out alias)
    u16* wqkv = (u16*)(ws + 16777216);   // 16.8 MB: wqT|wkT|wvT contiguous
    u16* wqT  = (u16*)(ws + 16777216);
    u16* wkT  = (u16*)(ws + 25165824);
    u16* wvT  = (u16*)(ws + 29360128);
    u16* woT  = (u16*)(ws + 33554432);   // 8.4 MB
    u16* qb   = (u16*)(ws + 41943040);   // 16.8 MB
    u16* kb   = (u16*)(ws + 58720256);   // 8.4 MB
    u16* vT   = (u16*)(ws + 67108864);   // 8.4 MB   total 75.5 MB
    u16* ao   = xb;                      // alias: x_bf16 dead after QKV gemm

    cvt_x<<<dim3(8192), dim3(256), 0, stream>>>(x, xb, 2097152);
    transpose_cvt4<<<dim3(32, 32, 4), dim3(256), 0, stream>>>(Wq, Wk, Wv, Wo,
                                                              wqT, wkT, wvT, woT);

    gemm_qkv8<<<dim3(256), dim3(512), 0, stream>>>(xb, wqkv, fc, fs, qb, kb, vT);

    attn_kernel<<<dim3(16, 32), dim3(256), 0, stream>>>(qb, kb, vT, fc, fs, ao);

    gemm_wo8<<<dim3(256), dim3(512), 0, stream>>>(ao, woT, out);
}

// Round 16
// 226.221 us; speedup vs baseline: 1.0899x; 1.0093x over previous
//
#include <hip/hip_runtime.h>
#include <stdint.h>

#define DI __device__ __forceinline__

typedef unsigned short u16;
typedef unsigned int   u32;
typedef __attribute__((ext_vector_type(8))) short short8;
typedef __attribute__((ext_vector_type(4))) float f32x4;

// ---- constants (problem shape hardcoded) ----
// B=2, S=2048, HID=2048, HQ=16, HKV=8, D=128

DI u16 f2bf(float f) {
    u32 u = __float_as_uint(f);
    u32 r = u + 0x7fff + ((u >> 16) & 1);   // RNE
    return (u16)(r >> 16);
}
DI u32 pk2bf(float a, float b) {
    return (u32)f2bf(a) | ((u32)f2bf(b) << 16);
}
DI float bf2f(u16 h) { return __uint_as_float(((u32)h) << 16); }

DI f32x4 mfma16(short8 a, short8 b, f32x4 c) {
    return __builtin_amdgcn_mfma_f32_16x16x32_bf16(a, b, c, 0, 0, 0);
}

DI void gload_lds16(const void* g, void* l) {
    __builtin_amdgcn_global_load_lds(
        (const __attribute__((address_space(1))) void*)g,
        (__attribute__((address_space(3))) void*)l, 16, 0, 0);
}

// rotate 4 bf16 (re,im) pairs by cos/sin (float4), scale folded into c/s
DI short8 rope8(short8 raw, const float* cp, const float* sp, float osc) {
    float4 c4 = *(const float4*)cp;
    float4 s4 = *(const float4*)sp;
    u32* rp = (u32*)&raw;
#pragma unroll
    for (int p = 0; p < 4; p++) {
        u32 v = rp[p];
        float re = __uint_as_float(v << 16);
        float im = __uint_as_float(v & 0xffff0000u);
        float cc = ((const float*)&c4)[p] * osc;
        float ss = ((const float*)&s4)[p] * osc;
        rp[p] = pk2bf(re * cc - im * ss, re * ss + im * cc);
    }
    return raw;
}

// ---- preproc: z=0..3 -> W [K][N] f32 -> WT [N][K] bf16; z=4 -> x f32->bf16 ----
__global__ __launch_bounds__(256) void preproc(const float* __restrict__ W0,
                                               const float* __restrict__ W1,
                                               const float* __restrict__ W2,
                                               const float* __restrict__ W3,
                                               const float* __restrict__ x,
                                               u16* __restrict__ D0,
                                               u16* __restrict__ D1,
                                               u16* __restrict__ D2,
                                               u16* __restrict__ D3,
                                               u16* __restrict__ xb) {
    if (blockIdx.z == 4) {               // cvt_x: 1024 blocks x 256 thr x 8 grp
        int base = (blockIdx.y * 32 + blockIdx.x) * 256 + threadIdx.x;
#pragma unroll
        for (int g = 0; g < 8; g++) {
            int i = base + g * 262144;
            float4 v = *(const float4*)(x + (size_t)i * 4);
            uint2 p; p.x = pk2bf(v.x, v.y); p.y = pk2bf(v.z, v.w);
            *(uint2*)(xb + (size_t)i * 4) = p;
        }
        return;
    }
    const float* W; u16* D; int N;
    switch (blockIdx.z) {
        case 0:  W = W0; D = D0; N = 2048; break;
        case 1:  W = W1; D = D1; N = 1024; break;
        case 2:  W = W2; D = D2; N = 1024; break;
        default: W = W3; D = D3; N = 2048; break;
    }
    if ((int)blockIdx.x >= (N >> 6)) return;
    const int K = 2048;
    __shared__ u16 tl[64][65];
    int tx = threadIdx.x & 15, ty = threadIdx.x >> 4;
    int tc = blockIdx.x * 64, tr = blockIdx.y * 64;
#pragma unroll
    for (int i = 0; i < 4; i++) {
        int r = tr + ty + i * 16;
        float4 v = *(const float4*)&W[(size_t)r * N + tc + tx * 4];
        tl[tx*4+0][ty+i*16] = f2bf(v.x);
        tl[tx*4+1][ty+i*16] = f2bf(v.y);
        tl[tx*4+2][ty+i*16] = f2bf(v.z);
        tl[tx*4+3][ty+i*16] = f2bf(v.w);
    }
    __syncthreads();
#pragma unroll
    for (int i = 0; i < 4; i++) {
        int n = tc + ty + i * 16;
        uint2 p;
        p.x = (u32)tl[ty+i*16][tx*4+0] | ((u32)tl[ty+i*16][tx*4+1] << 16);
        p.y = (u32)tl[ty+i*16][tx*4+2] | ((u32)tl[ty+i*16][tx*4+3] << 16);
        *(uint2*)&D[(size_t)n * K + tr + tx * 4] = p;
    }
}

// ---------------- 8-phase 256^2 QKV GEMM (T2+T3+T4+T5) --------
// ds_reads hoisted one phase ahead of their MFMA cluster (zero extra regs):
// ph1 reads all q0/q1 operands; ph2 MFMAs q1 then reloads aF<-rows m4-7;
// ph3/ph4 read nothing. Stage order + vmcnt placement unchanged (verified).
// K-RoPE fused into the K epilogue (pairs in adjacent lanes, shfl_xor(1)).
__global__ __launch_bounds__(512) void gemm_qkv8(const u16* __restrict__ A,
                                                 const u16* __restrict__ BT,
                                                 const float* __restrict__ fc,
                                                 const float* __restrict__ fs,
                                                 u16* __restrict__ Qo,
                                                 u16* __restrict__ Ko,
                                                 u16* __restrict__ Vo) {
    __shared__ __align__(16) u16 SM[65536];   // 128 KB
    char* smb = (char*)SM;
    const int tid = threadIdx.x;
    const int w = tid >> 6, l = tid & 63;
    const int l15 = l & 15, lh = l >> 4;
    const int wr = w >> 2, wc = w & 3;

    const int bid = blockIdx.x;
    const int sw = (bid & 7) * 32 + (bid >> 3);
    const int bx = sw & 15, by = sw >> 4;

    const char* Ag = (const char*)A  + (size_t)(by * 256) * 4096;
    const char* Bg = (const char*)BT + (size_t)(bx * 256) * 4096;

    const int r0 = tid >> 3;
    const int c0 = ((tid & 7) << 4) ^ (((tid >> 5) & 1) << 5);
    const int wb = w << 10;

#define STG_A(tt, bb, hh) do {                                              \
        const char* s_ = Ag + (size_t)((hh) * 128 + r0) * 4096 + (tt) * 128 + c0; \
        char* d_ = smb + (bb) * 65536 + (hh) * 16384 + wb;                  \
        gload_lds16(s_, d_);                                                \
        gload_lds16(s_ + (size_t)64 * 4096, d_ + 8192);                     \
    } while (0)
#define STG_B(tt, bb, hh) do {                                              \
        const char* s_ = Bg + (size_t)((hh) * 128 + r0) * 4096 + (tt) * 128 + c0; \
        char* d_ = smb + (bb) * 65536 + 32768 + (hh) * 16384 + wb;          \
        gload_lds16(s_, d_);                                                \
        gload_lds16(s_ + (size_t)64 * 4096, d_ + 8192);                     \
    } while (0)

    const int aoff = l15 * 128 + ((lh * 16) ^ (((l15 >> 2) & 1) << 5));

    const f32x4 fz = {0.f, 0.f, 0.f, 0.f};
    f32x4 acc[8][4];
#pragma unroll
    for (int m = 0; m < 8; m++)
#pragma unroll
        for (int n = 0; n < 4; n++) acc[m][n] = fz;

    STG_A(0, 0, 0); STG_A(0, 0, 1); STG_B(0, 0, 0); STG_B(0, 0, 1);
    STG_A(1, 1, 0);
    asm volatile("s_waitcnt vmcnt(2)" ::: "memory");
    __builtin_amdgcn_s_barrier();

    for (int t = 0; t < 32; ++t) {
        const int cur = t & 1;
        const int t1 = t + 1 < 32 ? t + 1 : 31;
        const int t2 = t + 2 < 32 ? t + 2 : 31;
        const char* Ab = smb + cur * 65536 + wr * 16384 + aoff;
        const char* Bb = smb + cur * 65536 + 32768 + (wc >> 1) * 16384
                         + (wc & 1) * 8192 + aoff;
        short8 aF[4][2], bF[4][2];

        // ---- ph1: stage A(t1,h1); read aF(m0-3) + bF(n0-3); MFMA q0 (m0-3 x n0-1)
        STG_A(t1, cur ^ 1, 1);
#pragma unroll
        for (int m = 0; m < 4; m++) {
            aF[m][0] = *(const short8*)(Ab + m * 2048);
            aF[m][1] = *(const short8*)(Ab + m * 2048 + 64);
        }
#pragma unroll
        for (int n = 0; n < 4; n++) {
            bF[n][0] = *(const short8*)(Bb + n * 2048);
            bF[n][1] = *(const short8*)(Bb + n * 2048 + 64);
        }
        __builtin_amdgcn_s_setprio(1);
#pragma unroll
        for (int m = 0; m < 4; m++)
#pragma unroll
            for (int n = 0; n < 2; n++) {
                acc[m][n] = mfma16(aF[m][0], bF[n][0], acc[m][n]);
                acc[m][n] = mfma16(aF[m][1], bF[n][1], acc[m][n]);
            }
        __builtin_amdgcn_s_setprio(0);
        __builtin_amdgcn_s_barrier();

        // ---- ph2: stage B(t1,h0); MFMA q1 (m0-3 x n2-3); then reload aF<-m4-7
        STG_B(t1, cur ^ 1, 0);
        __builtin_amdgcn_s_setprio(1);
#pragma unroll
        for (int m = 0; m < 4; m++)
#pragma unroll
            for (int n = 2; n < 4; n++) {
                acc[m][n] = mfma16(aF[m][0], bF[n][0], acc[m][n]);
                acc[m][n] = mfma16(aF[m][1], bF[n][1], acc[m][n]);
            }
        __builtin_amdgcn_s_setprio(0);
#pragma unroll
        for (int m = 0; m < 4; m++) {
            aF[m][0] = *(const short8*)(Ab + (m + 4) * 2048);
            aF[m][1] = *(const short8*)(Ab + (m + 4) * 2048 + 64);
        }
        __builtin_amdgcn_s_barrier();

        // ---- ph3: stage B(t1,h1); MFMA q2 (m4-7 x n0-1); operands all resident
        STG_B(t1, cur ^ 1, 1);
        __builtin_amdgcn_s_setprio(1);
#pragma unroll
        for (int m = 0; m < 4; m++)
#pragma unroll
            for (int n = 0; n < 2; n++) {
                acc[m + 4][n] = mfma16(aF[m][0], bF[n][0], acc[m + 4][n]);
                acc[m + 4][n] = mfma16(aF[m][1], bF[n][1], acc[m + 4][n]);
            }
        __builtin_amdgcn_s_setprio(0);
        __builtin_amdgcn_s_barrier();

        // ---- ph4: stage A(t2,cur,h0); MFMA q3 (m4-7 x n2-3); vmcnt(2)
        STG_A(t2, cur, 0);
        __builtin_amdgcn_s_setprio(1);
#pragma unroll
        for (int m = 0; m < 4; m++)
#pragma unroll
            for (int n = 2; n < 4; n++) {
                acc[m + 4][n] = mfma16(aF[m][0], bF[n][0], acc[m + 4][n]);
                acc[m + 4][n] = mfma16(aF[m][1], bF[n][1], acc[m + 4][n]);
            }
        __builtin_amdgcn_s_setprio(0);
        asm volatile("s_waitcnt vmcnt(2)" ::: "memory");
        __builtin_amdgcn_s_barrier();
    }
#undef STG_A
#undef STG_B

    const int rbase = by * 256 + wr * 128 + lh * 4;
    const int cbase = bx * 256 + wc * 64 + l15;
    if (bx < 8) {                       // Q [tok][2048]
#pragma unroll
        for (int m = 0; m < 8; m++)
#pragma unroll
            for (int j = 0; j < 4; j++) {
                size_t ro = (size_t)(rbase + m * 16 + j) * 2048 + cbase;
#pragma unroll
                for (int n = 0; n < 4; n++)
                    Qo[ro + n * 16] = f2bf(acc[m][n][j]);
            }
    } else if (bx < 12) {               // K [tok][1024], RoPE fused
        const int ck = cbase - 2048;
        const bool odd = (l15 & 1) != 0;
#pragma unroll
        for (int m = 0; m < 8; m++)
#pragma unroll
            for (int j = 0; j < 4; j++) {
                const int tok = rbase + m * 16 + j;
                const int s = tok & 2047;
                const float* fcb = fc + s * 64;
                const float* fsb = fs + s * 64;
                size_t ro = (size_t)tok * 1024 + ck;
#pragma unroll
                for (int n = 0; n < 4; n++) {
                    const int j2 = ((ck + n * 16) & 127) >> 1;
                    float own = acc[m][n][j];
                    float prt = __shfl_xor(own, 1);
                    float c = fcb[j2], sn = fsb[j2];
                    float out = odd ? (prt * sn + own * c)
                                    : (own * c - prt * sn);
                    Ko[ro + n * 16] = f2bf(out);
                }
            }
    } else {                            // V -> V^T[b][h2][d][s]
#pragma unroll
        for (int m = 0; m < 8; m++)
#pragma unroll
            for (int n = 0; n < 4; n++) {
                int tok = rbase + m * 16;
                int c = cbase + n * 16 - 3072;
                int bb2 = tok >> 11, ss = tok & 2047;
                int h2 = c >> 7, d = c & 127;
                uint2 v;
                v.x = pk2bf(acc[m][n][0], acc[m][n][1]);
                v.y = pk2bf(acc[m][n][2], acc[m][n][3]);
                *(uint2*)(Vo + (size_t)((bb2 * 8 + h2) * 128 + d) * 2048 + ss) = v;
            }
    }
}

// ---------------- Wo GEMM, 2-phase counted-vmcnt (BM=128 BN=256) ----------
// bF[2-3] reads hoisted into ph1 so ph2's MFMA starts stall-free.
__global__ __launch_bounds__(512) void gemm_wo8(const u16* __restrict__ A,
                                                const u16* __restrict__ BT,
                                                float* __restrict__ Of) {
    __shared__ __align__(16) u16 SM[49152];   // 96 KB
    char* smb = (char*)SM;
    const int tid = threadIdx.x;
    const int w = tid >> 6, l = tid & 63;
    const int l15 = l & 15, lh = l >> 4;
    const int wr = w >> 2, wc = w & 3;        // 2M x 4N

    const int bid = blockIdx.x;
    const int sw = (bid & 7) * 32 + (bid >> 3);
    const int bx = sw & 7, by = sw >> 3;      // bx: 8 N-tiles, by: 32 M-tiles

    const char* Ag = (const char*)A  + (size_t)(by * 128) * 4096;
    const char* Bg = (const char*)BT + (size_t)(bx * 256) * 4096;

    const int r0 = tid >> 3;                                   // 64 rows/issue
    const int c0 = ((tid & 7) << 4) ^ (((tid >> 5) & 1) << 5); // src pre-swizzle
    const int wb = w << 10;

#define STG_WA(tt, bb) do {                                                 \
        const char* s_ = Ag + (size_t)r0 * 4096 + (tt) * 128 + c0;          \
        char* d_ = smb + (bb) * 49152 + wb;                                 \
        gload_lds16(s_, d_);                                                \
        gload_lds16(s_ + (size_t)64 * 4096, d_ + 8192);                     \
    } while (0)
#define STG_WB(tt, bb) do {                                                 \
        const char* s_ = Bg + (size_t)r0 * 4096 + (tt) * 128 + c0;          \
        char* d_ = smb + (bb) * 49152 + 16384 + wb;                         \
        gload_lds16(s_, d_);                                                \
        gload_lds16(s_ + (size_t)64 * 4096, d_ + 8192);                     \
        gload_lds16(s_ + (size_t)128 * 4096, d_ + 16384);                   \
        gload_lds16(s_ + (size_t)192 * 4096, d_ + 24576);                   \
    } while (0)

    const int aoff = l15 * 128 + ((lh * 16) ^ (((l15 >> 2) & 1) << 5));

    const f32x4 fz = {0.f, 0.f, 0.f, 0.f};
    f32x4 acc[4][4];
#pragma unroll
    for (int m = 0; m < 4; m++)
#pragma unroll
        for (int n = 0; n < 4; n++) acc[m][n] = fz;

    STG_WA(0, 0); STG_WB(0, 0);
    STG_WA(1, 1);
    asm volatile("s_waitcnt vmcnt(2)" ::: "memory");
    __builtin_amdgcn_s_barrier();

    for (int t = 0; t < 32; ++t) {
        const int cur = t & 1;
        const int t1 = t + 1 < 32 ? t + 1 : 31;
        const int t2 = t + 2 < 32 ? t + 2 : 31;
        const char* Ab = smb + cur * 49152 + wr * 8192 + aoff;
        const char* Bb = smb + cur * 49152 + 16384 + wc * 8192 + aoff;
        short8 aF[4][2], bF[4][2];

        // ---- ph1: stage B(t+1); read A(all) + B(all 4); MFMA n0-1
        STG_WB(t1, cur ^ 1);
#pragma unroll
        for (int m = 0; m < 4; m++) {
            aF[m][0] = *(const short8*)(Ab + m * 2048);
            aF[m][1] = *(const short8*)(Ab + m * 2048 + 64);
        }
#pragma unroll
        for (int n = 0; n < 4; n++) {
            bF[n][0] = *(const short8*)(Bb + n * 2048);
            bF[n][1] = *(const short8*)(Bb + n * 2048 + 64);
        }
        __builtin_amdgcn_s_setprio(1);
#pragma unroll
        for (int m = 0; m < 4; m++)
#pragma unroll
            for (int n = 0; n < 2; n++) {
                acc[m][n] = mfma16(aF[m][0], bF[n][0], acc[m][n]);
                acc[m][n] = mfma16(aF[m][1], bF[n][1], acc[m][n]);
            }
        __builtin_amdgcn_s_setprio(0);
        __builtin_amdgcn_s_barrier();

        // ---- ph2: stage A(t+2) into cur (A consumed in ph1); MFMA n2-3
        STG_WA(t2, cur);
        __builtin_amdgcn_s_setprio(1);
#pragma unroll
        for (int m = 0; m < 4; m++)
#pragma unroll
            for (int n = 2; n < 4; n++) {
                acc[m][n] = mfma16(aF[m][0], bF[n][0], acc[m][n]);
                acc[m][n] = mfma16(aF[m][1], bF[n][1], acc[m][n]);
            }
        __builtin_amdgcn_s_setprio(0);
        asm volatile("s_waitcnt vmcnt(2)" ::: "memory");
        __builtin_amdgcn_s_barrier();
    }
#undef STG_WA
#undef STG_WB

    const int rbase = by * 128 + wr * 64 + lh * 4;
    const int cbase = bx * 256 + wc * 64 + l15;
#pragma unroll
    for (int m = 0; m < 4; m++)
#pragma unroll
        for (int j = 0; j < 4; j++) {
            size_t ro = (size_t)(rbase + m * 16 + j) * 2048 + cbase;
#pragma unroll
            for (int n = 0; n < 4; n++)
                Of[ro + n * 16] = acc[m][n][j];
        }
}

// ---------------- flash attention (non-causal, GQA) ----------------
// R7-proven structure: grid (16 qtiles, 32 bh) x-major; block 256 = 4 waves;
// wave owns 32 q rows (2 groups sharing K/V frags); KVBLK=64 double-buffered;
// LDS 80KB -> 2 blocks/CU. RoPE-Q fused into Q load. exp2-domain softmax,
// defer-max THR=8, lane-local lsum reduced in epilogue.
// __launch_bounds__(256,2) — do NOT raise: min-waves 4 caps VGPR at 128 and
// spills the 64-reg accumulator (R8/R9: 455MB scratch writes, 4x slower).
__global__ __launch_bounds__(256, 2) void attn_kernel(const u16* __restrict__ Q,
                                                      const u16* __restrict__ Kg,
                                                      const u16* __restrict__ Vg,
                                                      const float* __restrict__ fc,
                                                      const float* __restrict__ fs,
                                                      u16* __restrict__ O) {
    __shared__ __align__(16) u16 Ks[2][8192];  // [buf][64 key][128 d] swizzled
    __shared__ __align__(16) u16 Vs[2][8192];  // [buf][128 d][64 s]  swizzled
    __shared__ __align__(16) u16 Ps[4][2048];  // per-wave [32 q][64 k] swizzled
    const int tid = threadIdx.x;
    const int w = tid >> 6, l = tid & 63;
    const int qt = blockIdx.x, bh = blockIdx.y;
    const int b = bh >> 4, h = bh & 15, h2 = h >> 1;
    const int l15 = l & 15, lh = l >> 4;

    char* KsB = (char*)&Ks[0][0];
    char* VsB = (char*)&Vs[0][0];
    char* PsB = (char*)&Ps[w][0];

    const char* Kbase = (const char*)Kg + (size_t)b * 2048 * 2048 + h2 * 256;
    const char* Vbase = (const char*)Vg + (size_t)(b * 8 + h2) * 128 * 4096;
    int krow[4], kcol[4], vrow[4], vcol[4];
#pragma unroll
    for (int c = 0; c < 4; c++) {
        int X = c * 4096 + tid * 16;
        krow[c] = X >> 8; kcol[c] = (X & 255) ^ ((krow[c] & 7) << 4);
        vrow[c] = X >> 7; vcol[c] = (X & 127) ^ ((vrow[c] & 7) << 4);
    }

#define STAGE(t, pb) do {                                               \
        const char* Kt = Kbase + (size_t)(t) * 131072;                  \
        const char* Vt = Vbase + (t) * 128;                             \
        char* kd = KsB + (pb) * 16384 + tid * 16;                       \
        char* vd = VsB + (pb) * 16384 + tid * 16;                       \
        _Pragma("unroll")                                               \
        for (int c = 0; c < 4; c++) {                                   \
            gload_lds16(Kt + krow[c] * 2048 + kcol[c], kd + c * 4096);  \
            gload_lds16(Vt + (size_t)vrow[c] * 4096 + vcol[c], vd + c * 4096); \
        }                                                               \
    } while (0)

    // Q fragments for both q-groups, RoPE applied in-register;
    // scale log2e/sqrt(128) folded into cos/sin
    const float OSC = 0.12751742987f;
    short8 qf0[4], qf1[4];
    {
        const int s0r = qt * 128 + w * 32 + l15;
        const int s1r = s0r + 16;
        const u16* qp0 = Q + ((size_t)(b * 2048 + s0r)) * 2048 + h * 128 + lh * 8;
        const u16* qp1 = Q + ((size_t)(b * 2048 + s1r)) * 2048 + h * 128 + lh * 8;
#pragma unroll
        for (int ks = 0; ks < 4; ks++) {
            qf0[ks] = rope8(*(const short8*)(qp0 + ks * 32),
                            &fc[s0r * 64 + ks * 16 + lh * 4],
                            &fs[s0r * 64 + ks * 16 + lh * 4], OSC);
            qf1[ks] = rope8(*(const short8*)(qp1 + ks * 32),
                            &fc[s1r * 64 + ks * 16 + lh * 4],
                            &fs[s1r * 64 + ks * 16 + lh * 4], OSC);
        }
    }

    const f32x4 fz = {0.f, 0.f, 0.f, 0.f};
    f32x4 o0[8], o1[8];
#pragma unroll
    for (int n = 0; n < 8; n++) { o0[n] = fz; o1[n] = fz; }
    float mrow0[4] = {-1e30f, -1e30f, -1e30f, -1e30f};
    float mrow1[4] = {-1e30f, -1e30f, -1e30f, -1e30f};
    float lsum0[4] = {0.f, 0.f, 0.f, 0.f};
    float lsum1[4] = {0.f, 0.f, 0.f, 0.f};

    STAGE(0, 0);

    for (int t = 0; t < 32; t++) {
        __syncthreads();                 // drains vmcnt(0): stage(t) landed
        const int pb = t & 1;
        if (t < 31) STAGE(t + 1, pb ^ 1);
        const char* kc = KsB + pb * 16384;
        const char* vc = VsB + pb * 16384;
        const int swz = (l15 & 7) << 4;

        // S = Q.K^T for both q-groups; K frags read ONCE
        f32x4 s0[4], s1[4];
#pragma unroll
        for (int ct = 0; ct < 4; ct++) {
            s0[ct] = fz; s1[ct] = fz;
#pragma unroll
            for (int ks = 0; ks < 4; ks++) {
                short8 kf = *(const short8*)(kc + ((ct * 16 + l15) << 8)
                                                + ((ks * 64 + lh * 16) ^ swz));
                s0[ct] = mfma16(qf0[ks], kf, s0[ct]);
                s1[ct] = mfma16(qf1[ks], kf, s1[ct]);
            }
        }

        // defer-max online softmax, both groups
        float pl0[4], pl1[4];
#pragma unroll
        for (int r = 0; r < 4; r++) {
            pl0[r] = fmaxf(fmaxf(s0[0][r], s0[1][r]), fmaxf(s0[2][r], s0[3][r]));
            pl1[r] = fmaxf(fmaxf(s1[0][r], s1[1][r]), fmaxf(s1[2][r], s1[3][r]));
        }
        bool grow = false;
#pragma unroll
        for (int r = 0; r < 4; r++)
            grow = grow || (pl0[r] > mrow0[r] + 8.f) || (pl1[r] > mrow1[r] + 8.f);
        if (__any(grow)) {
#pragma unroll
            for (int r = 0; r < 4; r++) {
                float mx = pl0[r];
                mx = fmaxf(mx, __shfl_xor(mx, 1));
                mx = fmaxf(mx, __shfl_xor(mx, 2));
                mx = fmaxf(mx, __shfl_xor(mx, 4));
                mx = fmaxf(mx, __shfl_xor(mx, 8));
                float mnew = fmaxf(mrow0[r], mx);
                float fsc = exp2f(mrow0[r] - mnew);
                mrow0[r] = mnew;
                lsum0[r] *= fsc;
#pragma unroll
                for (int n = 0; n < 8; n++) o0[n][r] *= fsc;
            }
#pragma unroll
            for (int r = 0; r < 4; r++) {
                float mx = pl1[r];
                mx = fmaxf(mx, __shfl_xor(mx, 1));
                mx = fmaxf(mx, __shfl_xor(mx, 2));
                mx = fmaxf(mx, __shfl_xor(mx, 4));
                mx = fmaxf(mx, __shfl_xor(mx, 8));
                float mnew = fmaxf(mrow1[r], mx);
                float fsc = exp2f(mrow1[r] - mnew);
                mrow1[r] = mnew;
                lsum1[r] *= fsc;
#pragma unroll
                for (int n = 0; n < 8; n++) o1[n][r] *= fsc;
            }
        }
        const int cb2 = l15 << 1;
#pragma unroll
        for (int r = 0; r < 4; r++) {
            float p0 = exp2f(s0[0][r] - mrow0[r]);
            float p1 = exp2f(s0[1][r] - mrow0[r]);
            float p2 = exp2f(s0[2][r] - mrow0[r]);
            float p3 = exp2f(s0[3][r] - mrow0[r]);
            lsum0[r] += (p0 + p1) + (p2 + p3);
            const int rw = lh * 4 + r;
            const int rb = rw << 7;
            const int sw2 = (rw & 7) << 4;
            *(u16*)(PsB + (rb + (( 0 + cb2) ^ sw2))) =
                (u16)((__float_as_uint(p0) + 0x8000u) >> 16);
            *(u16*)(PsB + (rb + ((32 + cb2) ^ sw2))) =
                (u16)((__float_as_uint(p1) + 0x8000u) >> 16);
            *(u16*)(PsB + (rb + ((64 + cb2) ^ sw2))) =
                (u16)((__float_as_uint(p2) + 0x8000u) >> 16);
            *(u16*)(PsB + (rb + ((96 + cb2) ^ sw2))) =
                (u16)((__float_as_uint(p3) + 0x8000u) >> 16);
        }
#pragma unroll
        for (int r = 0; r < 4; r++) {
            float p0 = exp2f(s1[0][r] - mrow1[r]);
            float p1 = exp2f(s1[1][r] - mrow1[r]);
            float p2 = exp2f(s1[2][r] - mrow1[r]);
            float p3 = exp2f(s1[3][r] - mrow1[r]);
            lsum1[r] += (p0 + p1) + (p2 + p3);
            const int rw = 16 + lh * 4 + r;
            const int rb = rw << 7;
            const int sw2 = (rw & 7) << 4;
            *(u16*)(PsB + (rb + (( 0 + cb2) ^ sw2))) =
                (u16)((__float_as_uint(p0) + 0x8000u) >> 16);
            *(u16*)(PsB + (rb + ((32 + cb2) ^ sw2))) =
                (u16)((__float_as_uint(p1) + 0x8000u) >> 16);
            *(u16*)(PsB + (rb + ((64 + cb2) ^ sw2))) =
                (u16)((__float_as_uint(p2) + 0x8000u) >> 16);
            *(u16*)(PsB + (rb + ((96 + cb2) ^ sw2))) =
                (u16)((__float_as_uint(p3) + 0x8000u) >> 16);
        }

        // PV for both groups; V frags read ONCE
#pragma unroll
        for (int ks2 = 0; ks2 < 2; ks2++) {
            short8 pf0 = *(const short8*)(PsB + ((l15 << 7)
                                + ((ks2 * 64 + lh * 16) ^ swz)));
            short8 pf1 = *(const short8*)(PsB + (((16 + l15) << 7)
                                + ((ks2 * 64 + lh * 16) ^ swz)));
#pragma unroll
            for (int n = 0; n < 8; n++) {
                short8 vf = *(const short8*)(vc + (((n * 16 + l15) << 7)
                                                  + ((ks2 * 64 + lh * 16) ^ swz)));
                o0[n] = mfma16(pf0, vf, o0[n]);
                o1[n] = mfma16(pf1, vf, o1[n]);
            }
        }
    }

    // epilogue: normalize and store
    const int q0 = qt * 128 + w * 32;
    const size_t ob0 = ((size_t)(b * 2048 + q0 + lh * 4)) * 2048 + h * 128 + l15;
#pragma unroll
    for (int r = 0; r < 4; r++) {
        float ls = lsum0[r];
        ls += __shfl_xor(ls, 1);
        ls += __shfl_xor(ls, 2);
        ls += __shfl_xor(ls, 4);
        ls += __shfl_xor(ls, 8);
        float li = 1.0f / ls;
#pragma unroll
        for (int n = 0; n < 8; n++)
            O[ob0 + (size_t)r * 2048 + n * 16] = f2bf(o0[n][r] * li);
    }
    const size_t ob1 = ob0 + (size_t)16 * 2048;
#pragma unroll
    for (int r = 0; r < 4; r++) {
        float ls = lsum1[r];
        ls += __shfl_xor(ls, 1);
        ls += __shfl_xor(ls, 2);
        ls += __shfl_xor(ls, 4);
        ls += __shfl_xor(ls, 8);
        float li = 1.0f / ls;
#pragma unroll
        for (int n = 0; n < 8; n++)
            O[ob1 + (size_t)r * 2048 + n * 16] = f2bf(o1[n][r] * li);
    }
#undef STAGE
}

// ---------------- launch ----------------
extern "C" void kernel_launch(void* const* d_in, const int* in_sizes, int n_in,
                              void* d_out, int out_size, void* d_ws, size_t ws_size,
                              hipStream_t stream) {
    const float* x  = (const float*)d_in[0];
    const float* Wq = (const float*)d_in[1];
    const float* Wk = (const float*)d_in[2];
    const float* Wv = (const float*)d_in[3];
    const float* Wo = (const float*)d_in[4];
    const float* fc = (const float*)d_in[5];
    const float* fs = (const float*)d_in[6];
    float* out = (float*)d_out;

    uint8_t* ws = (uint8_t*)d_ws;
    u16* xb   = (u16*)(ws + 0);          // 16.8 MB  (attn-out alias)
    u16* wqkv = (u16*)(ws + 16777216);   // 16.8 MB: wqT|wkT|wvT contiguous
    u16* wqT  = (u16*)(ws + 16777216);
    u16* wkT  = (u16*)(ws + 25165824);
    u16* wvT  = (u16*)(ws + 29360128);
    u16* woT  = (u16*)(ws + 33554432);   // 8.4 MB
    u16* qb   = (u16*)(ws + 41943040);   // 16.8 MB
    u16* kb   = (u16*)(ws + 58720256);   // 8.4 MB
    u16* vT   = (u16*)(ws + 67108864);   // 8.4 MB   total 75.5 MB
    u16* ao   = xb;                      // alias: x_bf16 dead after QKV gemm

    preproc<<<dim3(32, 32, 5), dim3(256), 0, stream>>>(Wq, Wk, Wv, Wo, x,
                                                       wqT, wkT, wvT, woT, xb);

    gemm_qkv8<<<dim3(256), dim3(512), 0, stream>>>(xb, wqkv, fc, fs, qb, kb, vT);

    attn_kernel<<<dim3(16, 32), dim3(256), 0, stream>>>(qb, kb, vT, fc, fs, ao);

    gemm_wo8<<<dim3(256), dim3(512), 0, stream>>>(ao, woT, out);
}